// Round 6
// baseline (196.047 us; speedup 1.0000x reference)
//
#include <hip/hip_runtime.h>
#include <hip/hip_bf16.h>

// Problem constants
#define BATCH  16384
#define DIM    512
#define NLAYER 3
#define NEXP   4
#define RANK   128

typedef __bf16 bf16_t;
typedef bf16_t bf16x8 __attribute__((ext_vector_type(8)));
typedef bf16_t bf16x4 __attribute__((ext_vector_type(4)));
typedef float  f32x4  __attribute__((ext_vector_type(4)));

__device__ __forceinline__ float tanh_fast(float x) {
    float e = __expf(2.0f * x);
    return 1.0f - 2.0f * __builtin_amdgcn_rcpf(e + 1.0f);
}
// XOR-swizzle 16B slots by row (bits 4..6): A-frag reads 2-way max (free)
__device__ __forceinline__ int swz(int row, int b) { return b ^ ((row & 7) << 4); }

__device__ __forceinline__ bf16x8 ldsr(const bf16_t* base, int row, int kb) {
    return *(const bf16x8*)((const char*)base + row * 1024 + swz(row, kb));
}
__device__ __forceinline__ void ldsw2(bf16_t* base, int row, int cb, bf16_t v) {
    *(bf16_t*)((char*)base + row * 1024 + swz(row, cb)) = v;
}
// LDS-only barrier: drain ds ops, do NOT drain vmcnt -> weight prefetches
// survive across barriers (no global-mem cross-wave communication in-kernel).
__device__ __forceinline__ void barrier_lds() {
    asm volatile("s_waitcnt lgkmcnt(0)" ::: "memory");
    __builtin_amdgcn_s_barrier();
}

// ---- prep: pack all weights into per-wave MFMA fragment stream order ----
// Wave wn owns output cols [wn*64, wn*64+64). Frag (ks,ni) = B for
// n-cols ni*16.. and k = ks*32.. ; every load is base + lane*16B.
__global__ void prep_pack(const float* __restrict__ Vs,
                          const float* __restrict__ Us,
                          const float* __restrict__ Cs,
                          bf16_t* __restrict__ Vp,
                          bf16_t* __restrict__ Up,
                          bf16_t* __restrict__ Cp) {
    int t = blockIdx.x * 256 + threadIdx.x;
    if (t < 98304) {                       // V: XV = xl @ Vcat (N=512,K=512)
        int lane = t & 63, ni = (t >> 6) & 3, ks = (t >> 8) & 15,
            wn = (t >> 12) & 7, l = t >> 15;
        int c = wn * 64 + ni * 16 + (lane & 15), e = c >> 7, r = c & 127;
        int d0 = ks * 32 + (lane >> 4) * 8;
        const float* src = Vs + ((size_t)(l * NEXP + e) * DIM + d0) * RANK + r;
        bf16x8 v;
        #pragma unroll
        for (int j = 0; j < 8; ++j) v[j] = (bf16_t)src[j * RANK];
        *(bf16x8*)(Vp + (size_t)t * 8) = v;
    } else if (t < 196608) {               // U: XU = XC @ Ucat^T (N=512,K=512)
        int q = t - 98304;
        int lane = q & 63, ni = (q >> 6) & 3, ks = (q >> 8) & 15,
            wn = (q >> 12) & 7, l = q >> 15;
        int d = wn * 64 + ni * 16 + (lane & 15);
        int k0 = ks * 32 + (lane >> 4) * 8, e = k0 >> 7, r0 = k0 & 127;
        const float* src = Us + ((size_t)(l * NEXP + e) * DIM + d) * RANK + r0;
        bf16x8 v;
        #pragma unroll
        for (int j = 0; j < 8; ++j) v[j] = (bf16_t)src[j];
        *(bf16x8*)(Up + (size_t)q * 8) = v;
    } else if (t < 221184) {               // C: XC = XV @ C^T (block-diag K)
        int q = t - 196608;
        int lane = q & 63, ni = (q >> 6) & 3, k4 = (q >> 8) & 3,
            wn = (q >> 10) & 7, l = q >> 13;
        int e = wn >> 1, rp = (wn & 1) * 64 + ni * 16 + (lane & 15);
        int s0 = k4 * 32 + (lane >> 4) * 8;
        const float* src = Cs + ((size_t)(l * NEXP + e) * RANK + rp) * RANK + s0;
        bf16x8 v;
        #pragma unroll
        for (int j = 0; j < 8; ++j) v[j] = (bf16_t)src[j];
        *(bf16x8*)(Cp + (size_t)q * 8) = v;
    }
}

// ---------------- fused 3-layer kernel ----------------
// 256 blocks x 64 rows x 512 threads (8 waves, N-split). Per layer 3 wide
// phases + 6 lgkm-only barriers. One reused 64KB LDS buffer holds
// xl -> XV -> XC; residual stays f32 in registers (256-VGPR budget, no
// spills: launch_bounds(512,1); single reused acc; x0 re-read from L3).

__global__ __launch_bounds__(512, 1)
void fused3(const float* __restrict__ x,     // (B, 512) f32 (= x0)
            const bf16_t* __restrict__ Vp,
            const bf16_t* __restrict__ Up,
            const bf16_t* __restrict__ Cp,
            const float* __restrict__ bb,    // [L][D]
            float* __restrict__ out)         // (B, 512) f32
{
    __shared__ __align__(16) char smem[65536];
    bf16_t* buf = (bf16_t*)smem;             // 64 rows x 1024 B, swizzled

    const int tid  = threadIdx.x;
    const int lane = tid & 63;
    const int wn   = tid >> 6;       // 0..7: wave's 64-col slice
    const int lr   = lane & 15;
    const int lg   = lane >> 4;
    const int m0   = blockIdx.x * 64;

    // ---- init: buf = bf16(x stripe); residual regs from x ----
    #pragma unroll
    for (int it = 0; it < 16; ++it) {
        int q = tid + 512 * it;                      // 8192 float4 groups
        int row = q >> 7, c4 = (q & 127) << 2;
        float4 v = *(const float4*)(x + (size_t)(m0 + row) * DIM + c4);
        bf16x4 b4 = { (bf16_t)v.x, (bf16_t)v.y, (bf16_t)v.z, (bf16_t)v.w };
        *(bf16x4*)((char*)buf + row * 1024 + swz(row, c4 * 2)) = b4;
    }
    f32x4 xlf[4][4];
    #pragma unroll
    for (int mi = 0; mi < 4; ++mi)
        #pragma unroll
        for (int ni = 0; ni < 4; ++ni)
            #pragma unroll
            for (int j = 0; j < 4; ++j) {
                int row = mi * 16 + lg * 4 + j, col = wn * 64 + ni * 16 + lr;
                xlf[mi][ni][j] = x[(size_t)(m0 + row) * DIM + col];
            }
    barrier_lds();

    #pragma unroll 1
    for (int l = 0; l < NLAYER; ++l) {
        const bf16_t* Vw = Vp + (((size_t)l * 8 + wn) << 15) + lane * 8;
        const bf16_t* Uw = Up + (((size_t)l * 8 + wn) << 15) + lane * 8;
        const bf16_t* Cw = Cp + (((size_t)l * 8 + wn) << 13) + lane * 8;

        f32x4 acc[4][4];                  // reused across the 3 phases

        // ---- ph1: XV = xl @ Vcat  (64 x 64-per-wave, K=512) ----
        #pragma unroll
        for (int mi = 0; mi < 4; ++mi)
            #pragma unroll
            for (int ni = 0; ni < 4; ++ni)
                acc[mi][ni] = (f32x4){0.f, 0.f, 0.f, 0.f};
        #pragma unroll 4
        for (int ks = 0; ks < 16; ++ks) {
            bf16x8 bv[4];
            #pragma unroll
            for (int ni = 0; ni < 4; ++ni)
                bv[ni] = *(const bf16x8*)(Vw + (ks * 4 + ni) * 512);
            #pragma unroll
            for (int mi = 0; mi < 4; ++mi) {
                bf16x8 av = ldsr(buf, mi * 16 + lr, ks * 64 + lg * 16);
                #pragma unroll
                for (int ni = 0; ni < 4; ++ni)
                    acc[mi][ni] = __builtin_amdgcn_mfma_f32_16x16x32_bf16(
                        av, bv[ni], acc[mi][ni], 0, 0, 0);
            }
        }
        // prefetch C k4=0 frags (stay in flight across lgkm-only barriers)
        bf16x8 cv0[4];
        #pragma unroll
        for (int ni = 0; ni < 4; ++ni)
            cv0[ni] = *(const bf16x8*)(Cw + ni * 512);
        barrier_lds();                               // B1: ph1 reads done
        #pragma unroll
        for (int mi = 0; mi < 4; ++mi)
            #pragma unroll
            for (int ni = 0; ni < 4; ++ni)
                #pragma unroll
                for (int j = 0; j < 4; ++j)
                    ldsw2(buf, mi * 16 + lg * 4 + j,
                          (wn * 64 + ni * 16 + lr) * 2,
                          (bf16_t)tanh_fast(acc[mi][ni][j]));
        barrier_lds();                               // B2: XV visible

        // ---- ph2: XC = XV @ C^T (block-diag; wave's K = own expert) ----
        const int eb = (wn >> 1) * 256;              // expert K-base, bytes
        #pragma unroll
        for (int mi = 0; mi < 4; ++mi)
            #pragma unroll
            for (int ni = 0; ni < 4; ++ni)
                acc[mi][ni] = (f32x4){0.f, 0.f, 0.f, 0.f};
        #pragma unroll
        for (int k4 = 0; k4 < 4; ++k4) {
            bf16x8 av[4];
            #pragma unroll
            for (int mi = 0; mi < 4; ++mi)
                av[mi] = ldsr(buf, mi * 16 + lr, eb + k4 * 64 + lg * 16);
            #pragma unroll
            for (int ni = 0; ni < 4; ++ni) {
                bf16x8 bv = (k4 == 0) ? cv0[ni]
                          : *(const bf16x8*)(Cw + (k4 * 4 + ni) * 512);
                #pragma unroll
                for (int mi = 0; mi < 4; ++mi)
                    acc[mi][ni] = __builtin_amdgcn_mfma_f32_16x16x32_bf16(
                        av[mi], bv, acc[mi][ni], 0, 0, 0);
            }
        }
        // prefetch U ks=0 frags
        bf16x8 uv0[4];
        #pragma unroll
        for (int ni = 0; ni < 4; ++ni)
            uv0[ni] = *(const bf16x8*)(Uw + ni * 512);
        barrier_lds();                               // B3: XV reads done
        #pragma unroll
        for (int mi = 0; mi < 4; ++mi)
            #pragma unroll
            for (int ni = 0; ni < 4; ++ni)
                #pragma unroll
                for (int j = 0; j < 4; ++j)
                    ldsw2(buf, mi * 16 + lg * 4 + j,
                          (wn * 64 + ni * 16 + lr) * 2,
                          (bf16_t)tanh_fast(acc[mi][ni][j]));
        barrier_lds();                               // B4: XC visible

        // ---- ph3: xu = XC @ Ucat^T  (64 x 64-per-wave, K=512 concat) ----
        #pragma unroll
        for (int mi = 0; mi < 4; ++mi)
            #pragma unroll
            for (int ni = 0; ni < 4; ++ni)
                acc[mi][ni] = (f32x4){0.f, 0.f, 0.f, 0.f};
        #pragma unroll 4
        for (int ks = 0; ks < 16; ++ks) {
            bf16x8 av[4];
            #pragma unroll
            for (int mi = 0; mi < 4; ++mi)
                av[mi] = ldsr(buf, mi * 16 + lr, ks * 64 + lg * 16);
            #pragma unroll
            for (int ni = 0; ni < 4; ++ni) {
                bf16x8 bv = (ks == 0) ? uv0[ni]
                          : *(const bf16x8*)(Uw + (ks * 4 + ni) * 512);
                #pragma unroll
                for (int mi = 0; mi < 4; ++mi)
                    acc[mi][ni] = __builtin_amdgcn_mfma_f32_16x16x32_bf16(
                        av[mi], bv, acc[mi][ni], 0, 0, 0);
            }
        }

        // ---- residual: xl += x0 * (xu + E*bias); x0 re-read (L2/L3-hot) ----
        const float* bl = bb + l * DIM;
        #pragma unroll
        for (int ni = 0; ni < 4; ++ni) {
            int col = wn * 64 + ni * 16 + lr;
            float b4v = 4.0f * bl[col];
            #pragma unroll
            for (int mi = 0; mi < 4; ++mi)
                #pragma unroll
                for (int j = 0; j < 4; ++j) {
                    int row = mi * 16 + lg * 4 + j;
                    float x0v = x[(size_t)(m0 + row) * DIM + col];
                    xlf[mi][ni][j] += x0v * (acc[mi][ni][j] + b4v);
                }
        }
        if (l < NLAYER - 1) {
            barrier_lds();                           // B5: ph3 reads done
            #pragma unroll
            for (int mi = 0; mi < 4; ++mi)
                #pragma unroll
                for (int ni = 0; ni < 4; ++ni)
                    #pragma unroll
                    for (int j = 0; j < 4; ++j)
                        ldsw2(buf, mi * 16 + lg * 4 + j,
                              (wn * 64 + ni * 16 + lr) * 2,
                              (bf16_t)xlf[mi][ni][j]);
            barrier_lds();                           // B6: new xl visible
        }
    }

    // ---- epilogue: final residual from regs ----
    #pragma unroll
    for (int mi = 0; mi < 4; ++mi)
        #pragma unroll
        for (int ni = 0; ni < 4; ++ni)
            #pragma unroll
            for (int j = 0; j < 4; ++j) {
                int row = mi * 16 + lg * 4 + j, col = wn * 64 + ni * 16 + lr;
                out[(size_t)(m0 + row) * DIM + col] = xlf[mi][ni][j];
            }
}

// ---------------- host ----------------

extern "C" void kernel_launch(void* const* d_in, const int* in_sizes, int n_in,
                              void* d_out, int out_size, void* d_ws, size_t ws_size,
                              hipStream_t stream) {
    const float* x  = (const float*)d_in[0];   // (B, D)
    const float* Us = (const float*)d_in[1];   // (L, E, D, R)
    const float* Cs = (const float*)d_in[2];   // (L, E, R, R)
    const float* Vs = (const float*)d_in[3];   // (L, E, D, R)
    // d_in[4] = G: softmax over singleton axis == 1.0 -> unused
    const float* bb = (const float*)d_in[5];   // (L, D)
    float* out = (float*)d_out;

    bf16_t* Vp = (bf16_t*)d_ws;                // 786432 bf16
    bf16_t* Up = Vp + 786432;                  // 786432 bf16
    bf16_t* Cp = Up + 786432;                  // 196608 bf16

    prep_pack<<<864, 256, 0, stream>>>(Vs, Us, Cs, Vp, Up, Cp);
    fused3<<<BATCH / 64, 512, 0, stream>>>(x, Vp, Up, Cp, bb, out);
}

// Round 7
// 153.093 us; speedup vs baseline: 1.2806x; 1.2806x over previous
//
#include <hip/hip_runtime.h>
#include <hip/hip_bf16.h>

// Problem constants
#define BATCH  16384
#define DIM    512
#define NLAYER 3
#define NEXP   4
#define RANK   128

typedef __bf16 bf16_t;
typedef bf16_t bf16x8 __attribute__((ext_vector_type(8)));
typedef bf16_t bf16x4 __attribute__((ext_vector_type(4)));
typedef float  f32x4  __attribute__((ext_vector_type(4)));

__device__ __forceinline__ float tanh_fast(float x) {
    float e = __expf(2.0f * x);
    return 1.0f - 2.0f * __builtin_amdgcn_rcpf(e + 1.0f);
}
// XOR-swizzle 16B slots by row (bits 4..6): A-frag reads 2-way max (free)
__device__ __forceinline__ int swz(int row, int b) { return b ^ ((row & 7) << 4); }

__device__ __forceinline__ bf16x8 ldsr(const bf16_t* base, int row, int kb) {
    return *(const bf16x8*)((const char*)base + row * 1024 + swz(row, kb));
}
__device__ __forceinline__ void ldsw2(bf16_t* base, int row, int cb, bf16_t v) {
    *(bf16_t*)((char*)base + row * 1024 + swz(row, cb)) = v;
}
// LDS-only barrier: drain ds ops, do NOT drain vmcnt -> weight prefetches
// survive across barriers (no global-mem cross-wave communication in-kernel).
__device__ __forceinline__ void barrier_lds() {
    asm volatile("s_waitcnt lgkmcnt(0)" ::: "memory");
    __builtin_amdgcn_s_barrier();
}

// ---- prep: pack all weights into per-wave MFMA fragment stream order ----
// Wave wn owns output cols [wn*64, wn*64+64). Frag (ks,ni) = B for
// n-cols ni*16.. and k = ks*32.. ; every load is base + lane*16B.
__global__ void prep_pack(const float* __restrict__ Vs,
                          const float* __restrict__ Us,
                          const float* __restrict__ Cs,
                          bf16_t* __restrict__ Vp,
                          bf16_t* __restrict__ Up,
                          bf16_t* __restrict__ Cp) {
    int t = blockIdx.x * 256 + threadIdx.x;
    if (t < 98304) {                       // V: XV = xl @ Vcat (N=512,K=512)
        int lane = t & 63, ni = (t >> 6) & 3, ks = (t >> 8) & 15,
            wn = (t >> 12) & 7, l = t >> 15;
        int c = wn * 64 + ni * 16 + (lane & 15), e = c >> 7, r = c & 127;
        int d0 = ks * 32 + (lane >> 4) * 8;
        const float* src = Vs + ((size_t)(l * NEXP + e) * DIM + d0) * RANK + r;
        bf16x8 v;
        #pragma unroll
        for (int j = 0; j < 8; ++j) v[j] = (bf16_t)src[j * RANK];
        *(bf16x8*)(Vp + (size_t)t * 8) = v;
    } else if (t < 196608) {               // U: XU = XC @ Ucat^T (N=512,K=512)
        int q = t - 98304;
        int lane = q & 63, ni = (q >> 6) & 3, ks = (q >> 8) & 15,
            wn = (q >> 12) & 7, l = q >> 15;
        int d = wn * 64 + ni * 16 + (lane & 15);
        int k0 = ks * 32 + (lane >> 4) * 8, e = k0 >> 7, r0 = k0 & 127;
        const float* src = Us + ((size_t)(l * NEXP + e) * DIM + d) * RANK + r0;
        bf16x8 v;
        #pragma unroll
        for (int j = 0; j < 8; ++j) v[j] = (bf16_t)src[j];
        *(bf16x8*)(Up + (size_t)q * 8) = v;
    } else if (t < 221184) {               // C: XC = XV @ C^T (block-diag K)
        int q = t - 196608;
        int lane = q & 63, ni = (q >> 6) & 3, k4 = (q >> 8) & 3,
            wn = (q >> 10) & 7, l = q >> 13;
        int e = wn >> 1, rp = (wn & 1) * 64 + ni * 16 + (lane & 15);
        int s0 = k4 * 32 + (lane >> 4) * 8;
        const float* src = Cs + ((size_t)(l * NEXP + e) * RANK + rp) * RANK + s0;
        bf16x8 v;
        #pragma unroll
        for (int j = 0; j < 8; ++j) v[j] = (bf16_t)src[j];
        *(bf16x8*)(Cp + (size_t)q * 8) = v;
    }
}

// ---------------- fused 3-layer kernel ----------------
// 256 blocks x 64 rows x 512 threads (8 waves, N-split). Per layer 3 wide
// phases + 6 lgkm-only barriers. One reused 64KB LDS buffer holds
// xl -> XV -> XC; residual f32 + x0 bf16 in registers.
// amdgpu_waves_per_eu(2,2): exactly 2 waves/EU (our real occupancy) ->
// 256-VGPR allocator budget -> no scratch spills (hipcc default caps at 128).

__global__ __launch_bounds__(512)
__attribute__((amdgpu_waves_per_eu(2, 2)))
void fused3(const float* __restrict__ x,     // (B, 512) f32 (= x0)
            const bf16_t* __restrict__ Vp,
            const bf16_t* __restrict__ Up,
            const bf16_t* __restrict__ Cp,
            const float* __restrict__ bb,    // [L][D]
            float* __restrict__ out)         // (B, 512) f32
{
    __shared__ __align__(16) char smem[65536];
    bf16_t* buf = (bf16_t*)smem;             // 64 rows x 1024 B, swizzled

    const int tid  = threadIdx.x;
    const int lane = tid & 63;
    const int wn   = tid >> 6;       // 0..7: wave's 64-col slice
    const int lr   = lane & 15;
    const int lg   = lane >> 4;
    const int m0   = blockIdx.x * 64;

    // ---- init: buf = bf16(x stripe); residual regs ----
    #pragma unroll
    for (int it = 0; it < 16; ++it) {
        int q = tid + 512 * it;                      // 8192 float4 groups
        int row = q >> 7, c4 = (q & 127) << 2;
        float4 v = *(const float4*)(x + (size_t)(m0 + row) * DIM + c4);
        bf16x4 b4 = { (bf16_t)v.x, (bf16_t)v.y, (bf16_t)v.z, (bf16_t)v.w };
        *(bf16x4*)((char*)buf + row * 1024 + swz(row, c4 * 2)) = b4;
    }
    f32x4  xlf[4][4];
    bf16x4 x0r[4][4];
    #pragma unroll
    for (int mi = 0; mi < 4; ++mi)
        #pragma unroll
        for (int ni = 0; ni < 4; ++ni)
            #pragma unroll
            for (int j = 0; j < 4; ++j) {
                int row = mi * 16 + lg * 4 + j, col = wn * 64 + ni * 16 + lr;
                float v = x[(size_t)(m0 + row) * DIM + col];
                xlf[mi][ni][j] = v;
                x0r[mi][ni][j] = (bf16_t)v;
            }
    barrier_lds();

    #pragma unroll 1
    for (int l = 0; l < NLAYER; ++l) {
        const bf16_t* Vw = Vp + (((size_t)l * 8 + wn) << 15) + lane * 8;
        const bf16_t* Uw = Up + (((size_t)l * 8 + wn) << 15) + lane * 8;
        const bf16_t* Cw = Cp + (((size_t)l * 8 + wn) << 13) + lane * 8;

        // ---- ph1: XV = xl @ Vcat  (64 x 64-per-wave, K=512) ----
        {
            f32x4 a1[4][4] = {};
            const bf16_t* vp = Vw;                   // sequential frag walk
            #pragma unroll 4
            for (int ks = 0; ks < 16; ++ks) {
                bf16x8 bv[4];
                #pragma unroll
                for (int ni = 0; ni < 4; ++ni)
                    bv[ni] = *(const bf16x8*)(vp + ni * 512);
                vp += 2048;
                #pragma unroll
                for (int mi = 0; mi < 4; ++mi) {
                    bf16x8 av = ldsr(buf, mi * 16 + lr, ks * 64 + lg * 16);
                    #pragma unroll
                    for (int ni = 0; ni < 4; ++ni)
                        a1[mi][ni] = __builtin_amdgcn_mfma_f32_16x16x32_bf16(
                            av, bv[ni], a1[mi][ni], 0, 0, 0);
                }
            }
            // prefetch C k4=0 frags (in flight across lgkm-only barriers)
            bf16x8 cv0[4];
            #pragma unroll
            for (int ni = 0; ni < 4; ++ni)
                cv0[ni] = *(const bf16x8*)(Cw + ni * 512);
            barrier_lds();                           // B1: ph1 reads done
            #pragma unroll
            for (int mi = 0; mi < 4; ++mi)
                #pragma unroll
                for (int ni = 0; ni < 4; ++ni)
                    #pragma unroll
                    for (int j = 0; j < 4; ++j)
                        ldsw2(buf, mi * 16 + lg * 4 + j,
                              (wn * 64 + ni * 16 + lr) * 2,
                              (bf16_t)tanh_fast(a1[mi][ni][j]));
            barrier_lds();                           // B2: XV visible

            // ---- ph2: XC = XV @ C^T (block-diag; wave's K = own expert) ----
            const int eb = (wn >> 1) * 256;          // expert K-base, bytes
            f32x4 a2[4][4] = {};
            #pragma unroll
            for (int k4 = 0; k4 < 4; ++k4) {
                bf16x8 av[4];
                #pragma unroll
                for (int mi = 0; mi < 4; ++mi)
                    av[mi] = ldsr(buf, mi * 16 + lr, eb + k4 * 64 + lg * 16);
                #pragma unroll
                for (int ni = 0; ni < 4; ++ni) {
                    bf16x8 bv = (k4 == 0) ? cv0[ni]
                              : *(const bf16x8*)(Cw + (k4 * 4 + ni) * 512);
                    #pragma unroll
                    for (int mi = 0; mi < 4; ++mi)
                        a2[mi][ni] = __builtin_amdgcn_mfma_f32_16x16x32_bf16(
                            av[mi], bv, a2[mi][ni], 0, 0, 0);
                }
            }
            // prefetch U ks=0 frags
            bf16x8 uv0[4];
            #pragma unroll
            for (int ni = 0; ni < 4; ++ni)
                uv0[ni] = *(const bf16x8*)(Uw + ni * 512);
            barrier_lds();                           // B3: XV reads done
            #pragma unroll
            for (int mi = 0; mi < 4; ++mi)
                #pragma unroll
                for (int ni = 0; ni < 4; ++ni)
                    #pragma unroll
                    for (int j = 0; j < 4; ++j)
                        ldsw2(buf, mi * 16 + lg * 4 + j,
                              (wn * 64 + ni * 16 + lr) * 2,
                              (bf16_t)tanh_fast(a2[mi][ni][j]));
            barrier_lds();                           // B4: XC visible

            // ---- ph3: xu = XC @ Ucat^T (64 x 64-per-wave, K=512 concat) ----
            f32x4 a3[4][4] = {};
            {   // ks = 0 uses prefetched uv0
                bf16x8 av[4];
                #pragma unroll
                for (int mi = 0; mi < 4; ++mi)
                    av[mi] = ldsr(buf, mi * 16 + lr, lg * 16);
                #pragma unroll
                for (int ni = 0; ni < 4; ++ni)
                    #pragma unroll
                    for (int mi = 0; mi < 4; ++mi)
                        a3[mi][ni] = __builtin_amdgcn_mfma_f32_16x16x32_bf16(
                            av[mi], uv0[ni], a3[mi][ni], 0, 0, 0);
            }
            const bf16_t* up = Uw + 2048;
            #pragma unroll 5
            for (int ks = 1; ks < 16; ++ks) {
                bf16x8 av[4], bv[4];
                #pragma unroll
                for (int ni = 0; ni < 4; ++ni)
                    bv[ni] = *(const bf16x8*)(up + ni * 512);
                up += 2048;
                #pragma unroll
                for (int mi = 0; mi < 4; ++mi)
                    av[mi] = ldsr(buf, mi * 16 + lr, ks * 64 + lg * 16);
                #pragma unroll
                for (int ni = 0; ni < 4; ++ni)
                    #pragma unroll
                    for (int mi = 0; mi < 4; ++mi)
                        a3[mi][ni] = __builtin_amdgcn_mfma_f32_16x16x32_bf16(
                            av[mi], bv[ni], a3[mi][ni], 0, 0, 0);
            }

            // ---- residual: xl += x0 * (xu + E*bias)   (gate == 1) ----
            const float* bl = bb + l * DIM;
            #pragma unroll
            for (int ni = 0; ni < 4; ++ni) {
                int col = wn * 64 + ni * 16 + lr;
                float b4v = 4.0f * bl[col];
                #pragma unroll
                for (int mi = 0; mi < 4; ++mi)
                    #pragma unroll
                    for (int j = 0; j < 4; ++j)
                        xlf[mi][ni][j] +=
                            (float)x0r[mi][ni][j] * (a3[mi][ni][j] + b4v);
            }
        }

        if (l < NLAYER - 1) {
            barrier_lds();                           // B5: ph3 reads done
            #pragma unroll
            for (int mi = 0; mi < 4; ++mi)
                #pragma unroll
                for (int ni = 0; ni < 4; ++ni)
                    #pragma unroll
                    for (int j = 0; j < 4; ++j)
                        ldsw2(buf, mi * 16 + lg * 4 + j,
                              (wn * 64 + ni * 16 + lr) * 2,
                              (bf16_t)xlf[mi][ni][j]);
            barrier_lds();                           // B6: new xl visible
        }
    }

    // ---- epilogue: final residual from regs ----
    #pragma unroll
    for (int mi = 0; mi < 4; ++mi)
        #pragma unroll
        for (int ni = 0; ni < 4; ++ni)
            #pragma unroll
            for (int j = 0; j < 4; ++j) {
                int row = mi * 16 + lg * 4 + j, col = wn * 64 + ni * 16 + lr;
                out[(size_t)(m0 + row) * DIM + col] = xlf[mi][ni][j];
            }
}

// ---------------- host ----------------

extern "C" void kernel_launch(void* const* d_in, const int* in_sizes, int n_in,
                              void* d_out, int out_size, void* d_ws, size_t ws_size,
                              hipStream_t stream) {
    const float* x  = (const float*)d_in[0];   // (B, D)
    const float* Us = (const float*)d_in[1];   // (L, E, D, R)
    const float* Cs = (const float*)d_in[2];   // (L, E, R, R)
    const float* Vs = (const float*)d_in[3];   // (L, E, D, R)
    // d_in[4] = G: softmax over singleton axis == 1.0 -> unused
    const float* bb = (const float*)d_in[5];   // (L, D)
    float* out = (float*)d_out;

    bf16_t* Vp = (bf16_t*)d_ws;                // 786432 bf16
    bf16_t* Up = Vp + 786432;                  // 786432 bf16
    bf16_t* Cp = Up + 786432;                  // 196608 bf16

    prep_pack<<<864, 256, 0, stream>>>(Vs, Us, Cs, Vp, Up, Cp);
    fused3<<<BATCH / 64, 512, 0, stream>>>(x, Vp, Up, Cp, bb, out);
}

// Round 8
// 117.226 us; speedup vs baseline: 1.6724x; 1.3060x over previous
//
#include <hip/hip_runtime.h>
#include <hip/hip_bf16.h>

// Problem constants
#define BATCH  16384
#define DIM    512
#define NLAYER 3
#define NEXP   4
#define RANK   128

typedef __bf16 bf16_t;
typedef bf16_t bf16x8 __attribute__((ext_vector_type(8)));
typedef bf16_t bf16x4 __attribute__((ext_vector_type(4)));
typedef float  f32x4  __attribute__((ext_vector_type(4)));

__device__ __forceinline__ float tanh_fast(float x) {
    float e = __expf(2.0f * x);
    return 1.0f - 2.0f * __builtin_amdgcn_rcpf(e + 1.0f);
}
// XOR-swizzle 16B slots by row (bits 4..6): A-frag reads 2-way max (free)
__device__ __forceinline__ int swz(int row, int b) { return b ^ ((row & 7) << 4); }

__device__ __forceinline__ bf16x8 ldsr(const bf16_t* base, int row, int kb) {
    return *(const bf16x8*)((const char*)base + row * 1024 + swz(row, kb));
}
__device__ __forceinline__ void ldsw2(bf16_t* base, int row, int cb, bf16_t v) {
    *(bf16_t*)((char*)base + row * 1024 + swz(row, cb)) = v;
}
// LDS-only barrier: drain ds ops, do NOT drain vmcnt -> weight loads
// survive across barriers (no global-mem cross-wave communication in-kernel).
__device__ __forceinline__ void barrier_lds() {
    asm volatile("s_waitcnt lgkmcnt(0)" ::: "memory");
    __builtin_amdgcn_s_barrier();
}

// ---- prep: pack all weights into per-wave MFMA fragment stream order ----
// Wave wn owns output cols [wn*64, wn*64+64). Frag (ks,ni) = B for
// n-cols ni*16.. and k = ks*32.. ; every load is base + lane*16B.
// (Row-count independent: identical to previous rounds.)
__global__ void prep_pack(const float* __restrict__ Vs,
                          const float* __restrict__ Us,
                          const float* __restrict__ Cs,
                          bf16_t* __restrict__ Vp,
                          bf16_t* __restrict__ Up,
                          bf16_t* __restrict__ Cp) {
    int t = blockIdx.x * 256 + threadIdx.x;
    if (t < 98304) {                       // V: XV = xl @ Vcat (N=512,K=512)
        int lane = t & 63, ni = (t >> 6) & 3, ks = (t >> 8) & 15,
            wn = (t >> 12) & 7, l = t >> 15;
        int c = wn * 64 + ni * 16 + (lane & 15), e = c >> 7, r = c & 127;
        int d0 = ks * 32 + (lane >> 4) * 8;
        const float* src = Vs + ((size_t)(l * NEXP + e) * DIM + d0) * RANK + r;
        bf16x8 v;
        #pragma unroll
        for (int j = 0; j < 8; ++j) v[j] = (bf16_t)src[j * RANK];
        *(bf16x8*)(Vp + (size_t)t * 8) = v;
    } else if (t < 196608) {               // U: XU = XC @ Ucat^T (N=512,K=512)
        int q = t - 98304;
        int lane = q & 63, ni = (q >> 6) & 3, ks = (q >> 8) & 15,
            wn = (q >> 12) & 7, l = q >> 15;
        int d = wn * 64 + ni * 16 + (lane & 15);
        int k0 = ks * 32 + (lane >> 4) * 8, e = k0 >> 7, r0 = k0 & 127;
        const float* src = Us + ((size_t)(l * NEXP + e) * DIM + d) * RANK + r0;
        bf16x8 v;
        #pragma unroll
        for (int j = 0; j < 8; ++j) v[j] = (bf16_t)src[j];
        *(bf16x8*)(Up + (size_t)q * 8) = v;
    } else if (t < 221184) {               // C: XC = XV @ C^T (block-diag K)
        int q = t - 196608;
        int lane = q & 63, ni = (q >> 6) & 3, k4 = (q >> 8) & 3,
            wn = (q >> 10) & 7, l = q >> 13;
        int e = wn >> 1, rp = (wn & 1) * 64 + ni * 16 + (lane & 15);
        int s0 = k4 * 32 + (lane >> 4) * 8;
        const float* src = Cs + ((size_t)(l * NEXP + e) * RANK + rp) * RANK + s0;
        bf16x8 v;
        #pragma unroll
        for (int j = 0; j < 8; ++j) v[j] = (bf16_t)src[j];
        *(bf16x8*)(Cp + (size_t)q * 8) = v;
    }
}

// ---------------- fused 3-layer kernel ----------------
// 512 blocks x 32 rows x 512 threads (8 waves, N-split) -> 2 blocks/CU,
// 16 waves/CU: independent blocks overlap each other's barriers.
// Per-thread state halved vs 64-row version: xlf[2][4]+x0r+acc ~ 110 VGPR,
// fits the 128 cap with NO scratch spills. One reused 32KB LDS buffer
// holds xl -> XV -> XC; weights stream global->reg (frag-packed).

__global__ __launch_bounds__(512)
void fused3(const float* __restrict__ x,     // (B, 512) f32 (= x0)
            const bf16_t* __restrict__ Vp,
            const bf16_t* __restrict__ Up,
            const bf16_t* __restrict__ Cp,
            const float* __restrict__ bb,    // [L][D]
            float* __restrict__ out)         // (B, 512) f32
{
    __shared__ __align__(16) char smem[32768];
    bf16_t* buf = (bf16_t*)smem;             // 32 rows x 1024 B, swizzled

    const int tid  = threadIdx.x;
    const int lane = tid & 63;
    const int wn   = tid >> 6;       // 0..7: wave's 64-col slice
    const int lr   = lane & 15;
    const int lg   = lane >> 4;
    const int m0   = blockIdx.x * 32;

    // ---- init: buf = bf16(x stripe); residual regs ----
    #pragma unroll
    for (int it = 0; it < 8; ++it) {
        int q = tid + 512 * it;                      // 4096 float4 groups
        int row = q >> 7, c4 = (q & 127) << 2;
        float4 v = *(const float4*)(x + (size_t)(m0 + row) * DIM + c4);
        bf16x4 b4 = { (bf16_t)v.x, (bf16_t)v.y, (bf16_t)v.z, (bf16_t)v.w };
        *(bf16x4*)((char*)buf + row * 1024 + swz(row, c4 * 2)) = b4;
    }
    f32x4  xlf[2][4];
    bf16x4 x0r[2][4];
    #pragma unroll
    for (int mi = 0; mi < 2; ++mi)
        #pragma unroll
        for (int ni = 0; ni < 4; ++ni)
            #pragma unroll
            for (int j = 0; j < 4; ++j) {
                int row = mi * 16 + lg * 4 + j, col = wn * 64 + ni * 16 + lr;
                float v = x[(size_t)(m0 + row) * DIM + col];
                xlf[mi][ni][j] = v;
                x0r[mi][ni][j] = (bf16_t)v;
            }
    barrier_lds();

    #pragma unroll 1
    for (int l = 0; l < NLAYER; ++l) {
        const bf16_t* Vw = Vp + (((size_t)l * 8 + wn) << 15) + lane * 8;
        const bf16_t* Uw = Up + (((size_t)l * 8 + wn) << 15) + lane * 8;
        const bf16_t* Cw = Cp + (((size_t)l * 8 + wn) << 13) + lane * 8;

        // ---- ph1: XV = xl @ Vcat  (32 x 64-per-wave, K=512) ----
        {
            f32x4 a1[2][4] = {};
            const bf16_t* vp = Vw;                   // sequential frag walk
            #pragma unroll 4
            for (int ks = 0; ks < 16; ++ks) {
                bf16x8 bv[4];
                #pragma unroll
                for (int ni = 0; ni < 4; ++ni)
                    bv[ni] = *(const bf16x8*)(vp + ni * 512);
                vp += 2048;
                #pragma unroll
                for (int mi = 0; mi < 2; ++mi) {
                    bf16x8 av = ldsr(buf, mi * 16 + lr, ks * 64 + lg * 16);
                    #pragma unroll
                    for (int ni = 0; ni < 4; ++ni)
                        a1[mi][ni] = __builtin_amdgcn_mfma_f32_16x16x32_bf16(
                            av, bv[ni], a1[mi][ni], 0, 0, 0);
                }
            }
            barrier_lds();                           // B1: ph1 reads done
            #pragma unroll
            for (int mi = 0; mi < 2; ++mi)
                #pragma unroll
                for (int ni = 0; ni < 4; ++ni)
                    #pragma unroll
                    for (int j = 0; j < 4; ++j)
                        ldsw2(buf, mi * 16 + lg * 4 + j,
                              (wn * 64 + ni * 16 + lr) * 2,
                              (bf16_t)tanh_fast(a1[mi][ni][j]));
            barrier_lds();                           // B2: XV visible
        }

        // ---- ph2: XC = XV @ C^T (block-diag; wave's K = own expert) ----
        {
            const int eb = (wn >> 1) * 256;          // expert K-base, bytes
            f32x4 a2[2][4] = {};
            #pragma unroll
            for (int k4 = 0; k4 < 4; ++k4) {
                bf16x8 av[2];
                #pragma unroll
                for (int mi = 0; mi < 2; ++mi)
                    av[mi] = ldsr(buf, mi * 16 + lr, eb + k4 * 64 + lg * 16);
                #pragma unroll
                for (int ni = 0; ni < 4; ++ni) {
                    bf16x8 bv = *(const bf16x8*)(Cw + (k4 * 4 + ni) * 512);
                    #pragma unroll
                    for (int mi = 0; mi < 2; ++mi)
                        a2[mi][ni] = __builtin_amdgcn_mfma_f32_16x16x32_bf16(
                            av[mi], bv, a2[mi][ni], 0, 0, 0);
                }
            }
            barrier_lds();                           // B3: XV reads done
            #pragma unroll
            for (int mi = 0; mi < 2; ++mi)
                #pragma unroll
                for (int ni = 0; ni < 4; ++ni)
                    #pragma unroll
                    for (int j = 0; j < 4; ++j)
                        ldsw2(buf, mi * 16 + lg * 4 + j,
                              (wn * 64 + ni * 16 + lr) * 2,
                              (bf16_t)tanh_fast(a2[mi][ni][j]));
            barrier_lds();                           // B4: XC visible
        }

        // ---- ph3: xu = XC @ Ucat^T  (32 x 64-per-wave, K=512 concat) ----
        {
            f32x4 a3[2][4] = {};
            const bf16_t* up = Uw;
            #pragma unroll 4
            for (int ks = 0; ks < 16; ++ks) {
                bf16x8 bv[4];
                #pragma unroll
                for (int ni = 0; ni < 4; ++ni)
                    bv[ni] = *(const bf16x8*)(up + ni * 512);
                up += 2048;
                #pragma unroll
                for (int mi = 0; mi < 2; ++mi) {
                    bf16x8 av = ldsr(buf, mi * 16 + lr, ks * 64 + lg * 16);
                    #pragma unroll
                    for (int ni = 0; ni < 4; ++ni)
                        a3[mi][ni] = __builtin_amdgcn_mfma_f32_16x16x32_bf16(
                            av, bv[ni], a3[mi][ni], 0, 0, 0);
                }
            }

            // ---- residual: xl += x0 * (xu + E*bias)   (gate == 1) ----
            const float* bl = bb + l * DIM;
            #pragma unroll
            for (int ni = 0; ni < 4; ++ni) {
                int col = wn * 64 + ni * 16 + lr;
                float b4v = 4.0f * bl[col];
                #pragma unroll
                for (int mi = 0; mi < 2; ++mi)
                    #pragma unroll
                    for (int j = 0; j < 4; ++j)
                        xlf[mi][ni][j] +=
                            (float)x0r[mi][ni][j] * (a3[mi][ni][j] + b4v);
            }
        }

        if (l < NLAYER - 1) {
            barrier_lds();                           // B5: ph3 reads done
            #pragma unroll
            for (int mi = 0; mi < 2; ++mi)
                #pragma unroll
                for (int ni = 0; ni < 4; ++ni)
                    #pragma unroll
                    for (int j = 0; j < 4; ++j)
                        ldsw2(buf, mi * 16 + lg * 4 + j,
                              (wn * 64 + ni * 16 + lr) * 2,
                              (bf16_t)xlf[mi][ni][j]);
            barrier_lds();                           // B6: new xl visible
        }
    }

    // ---- epilogue: final residual from regs ----
    #pragma unroll
    for (int mi = 0; mi < 2; ++mi)
        #pragma unroll
        for (int ni = 0; ni < 4; ++ni)
            #pragma unroll
            for (int j = 0; j < 4; ++j) {
                int row = mi * 16 + lg * 4 + j, col = wn * 64 + ni * 16 + lr;
                out[(size_t)(m0 + row) * DIM + col] = xlf[mi][ni][j];
            }
}

// ---------------- host ----------------

extern "C" void kernel_launch(void* const* d_in, const int* in_sizes, int n_in,
                              void* d_out, int out_size, void* d_ws, size_t ws_size,
                              hipStream_t stream) {
    const float* x  = (const float*)d_in[0];   // (B, D)
    const float* Us = (const float*)d_in[1];   // (L, E, D, R)
    const float* Cs = (const float*)d_in[2];   // (L, E, R, R)
    const float* Vs = (const float*)d_in[3];   // (L, E, D, R)
    // d_in[4] = G: softmax over singleton axis == 1.0 -> unused
    const float* bb = (const float*)d_in[5];   // (L, D)
    float* out = (float*)d_out;

    bf16_t* Vp = (bf16_t*)d_ws;                // 786432 bf16
    bf16_t* Up = Vp + 786432;                  // 786432 bf16
    bf16_t* Cp = Up + 786432;                  // 196608 bf16

    prep_pack<<<864, 256, 0, stream>>>(Vs, Us, Cs, Vp, Up, Cp);
    fused3<<<BATCH / 32, 512, 0, stream>>>(x, Vp, Up, Cp, bb, out);
}